// Round 1
// baseline (2787.060 us; speedup 1.0000x reference)
//
#include <hip/hip_runtime.h>

namespace {

constexpr int ET   = 16;        // edges per block
constexpr int DSH  = 25;        // spherical-harmonic coeffs
constexpr int CCH  = 32;        // channels
constexpr int DROW = DSH * CCH; // 800 floats per edge-feature
constexpr int WELE = DSH * DSH; // 625 wigner elements

// (l,m) flattened index tables, compile-time
template<int M> struct MTab;
template<> struct MTab<1> { static constexpr int NL = 4; static constexpr int P[4] = {3, 7, 13, 21};  static constexpr int Ng[4] = {1, 5, 11, 19}; };
template<> struct MTab<2> { static constexpr int NL = 3; static constexpr int P[3] = {8, 14, 22};     static constexpr int Ng[3] = {4, 10, 18}; };
template<> struct MTab<3> { static constexpr int NL = 2; static constexpr int P[2] = {15, 23};        static constexpr int Ng[2] = {9, 17}; };
template<> struct MTab<4> { static constexpr int NL = 1; static constexpr int P[1] = {24};            static constexpr int Ng[1] = {16}; };

// SO(2) complex mixing for one m>0 block; all acc indices compile-time.
template<int M>
__device__ __forceinline__ void mix_m(const float* __restrict__ wr,
                                      const float* __restrict__ wi,
                                      const float* __restrict__ xr0,
                                      const float* __restrict__ xr1,
                                      float (&acc0)[25], float (&acc1)[25],
                                      int c)
{
    constexpr int NL = MTab<M>::NL;
    constexpr int D  = NL * 32;
    #pragma unroll
    for (int li = 0; li < NL; ++li) {
        const int rp_in = MTab<M>::P[li]  * 32;
        const int rn_in = MTab<M>::Ng[li] * 32;
        for (int ci = 0; ci < 32; ++ci) {
            const int k = li * 32 + ci;
            const float xp0 = xr0[rp_in + ci];
            const float xn0 = xr0[rn_in + ci];
            const float xp1 = xr1[rp_in + ci];
            const float xn1 = xr1[rn_in + ci];
            const float* wrp = wr + k * D + c;
            const float* wip = wi + k * D + c;
            #pragma unroll
            for (int lo = 0; lo < NL; ++lo) {
                const float vr = wrp[lo * 32];
                const float vi = wip[lo * 32];
                constexpr const int* PP = MTab<M>::P;
                constexpr const int* NN = MTab<M>::Ng;
                acc0[PP[lo]] = fmaf(xp0,  vr, acc0[PP[lo]]);
                acc0[PP[lo]] = fmaf(xn0, -vi, acc0[PP[lo]]);
                acc0[NN[lo]] = fmaf(xp0,  vi, acc0[NN[lo]]);
                acc0[NN[lo]] = fmaf(xn0,  vr, acc0[NN[lo]]);
                acc1[PP[lo]] = fmaf(xp1,  vr, acc1[PP[lo]]);
                acc1[PP[lo]] = fmaf(xn1, -vi, acc1[PP[lo]]);
                acc1[NN[lo]] = fmaf(xp1,  vi, acc1[NN[lo]]);
                acc1[NN[lo]] = fmaf(xn1,  vr, acc1[NN[lo]]);
            }
        }
    }
}

} // namespace

__launch_bounds__(256, 2)
__global__ void so2_fused_kernel(
    const float* __restrict__ x,    const float* __restrict__ wig,
    const float* __restrict__ efc,  const int* __restrict__ esrc,
    const int* __restrict__ edst,
    const float* __restrict__ w0,
    const float* __restrict__ w1r,  const float* __restrict__ w1i,
    const float* __restrict__ w2r,  const float* __restrict__ w2i,
    const float* __restrict__ w3r,  const float* __restrict__ w3i,
    const float* __restrict__ w4r,  const float* __restrict__ w4i,
    const float* __restrict__ fcw,  const float* __restrict__ fcb,
    float* __restrict__ out, int E)
{
    __shared__ float s_xr[ET * DROW];       // 51.2 KB: rotated features, then y in-place
    __shared__ float s_stage[DROW + 640];   // 5.76 KB: xe staging + wigner staging

    const int tid = threadIdx.x;
    const int e0  = blockIdx.x * ET;

    // ---------------- Phase 1: gather + rotate (xr = W @ x[src]) ----------------
    for (int s = 0; s < ET; ++s) {
        const int e   = min(e0 + s, E - 1);
        const int src = esrc[e];
        const float* xe  = x   + (size_t)src * DROW;
        const float* wgp = wig + (size_t)e   * WELE;
        for (int o = tid; o < DROW; o += 256) s_stage[o] = xe[o];
        for (int o = tid; o < WELE; o += 256) s_stage[DROW + o] = wgp[o];
        __syncthreads();
        for (int o = tid; o < DROW; o += 256) {
            const int i = o >> 5, cc = o & 31;
            float a = 0.f;
            #pragma unroll
            for (int j = 0; j < DSH; ++j)
                a = fmaf(s_stage[DROW + i * DSH + j], s_stage[j * 32 + cc], a);
            s_xr[s * DROW + o] = a;
        }
        __syncthreads();
    }

    // ---------------- Phase 2: per-thread radial scale + SO(2) mixing ----------------
    const int c    = tid & 31;
    const int slot = tid >> 5;          // 8 slot-groups; edges slot and slot+8
    const int ea = min(e0 + slot,     E - 1);
    const int eb = min(e0 + slot + 8, E - 1);

    // silu(edge_fc @ fc_w + fc_b) for this thread's channel, 5 l-values, 2 edges
    float sc0[5], sc1[5];
    {
        const float* f0 = efc + (size_t)ea * 64;
        const float* f1 = efc + (size_t)eb * 64;
        float a0[5], a1[5];
        #pragma unroll
        for (int l = 0; l < 5; ++l) { a0[l] = fcb[l * 32 + c]; a1[l] = a0[l]; }
        for (int k = 0; k < 64; ++k) {
            const float v0 = f0[k], v1 = f1[k];
            #pragma unroll
            for (int l = 0; l < 5; ++l) {
                const float wv = fcw[k * 160 + l * 32 + c];
                a0[l] = fmaf(v0, wv, a0[l]);
                a1[l] = fmaf(v1, wv, a1[l]);
            }
        }
        #pragma unroll
        for (int l = 0; l < 5; ++l) {
            sc0[l] = a0[l] / (1.f + expf(-a0[l]));
            sc1[l] = a1[l] / (1.f + expf(-a1[l]));
        }
    }

    float acc0[25], acc1[25];
    #pragma unroll
    for (int r = 0; r < 25; ++r) { acc0[r] = 0.f; acc1[r] = 0.f; }

    const float* xr0 = s_xr + slot * DROW;
    const float* xr1 = s_xr + (slot + 8) * DROW;

    // m = 0 block: real [160x160]
    {
        constexpr int R0[5] = {0, 2, 6, 12, 20};
        #pragma unroll
        for (int li = 0; li < 5; ++li) {
            const int rin = R0[li] * 32;
            for (int ci = 0; ci < 32; ++ci) {
                const float xv0 = xr0[rin + ci];
                const float xv1 = xr1[rin + ci];
                const float* wrp = w0 + (li * 32 + ci) * 160 + c;
                #pragma unroll
                for (int lo = 0; lo < 5; ++lo) {
                    const float wv = wrp[lo * 32];
                    acc0[R0[lo]] = fmaf(xv0, wv, acc0[R0[lo]]);
                    acc1[R0[lo]] = fmaf(xv1, wv, acc1[R0[lo]]);
                }
            }
        }
    }
    // m = 1..4 complex blocks
    mix_m<1>(w1r, w1i, xr0, xr1, acc0, acc1, c);
    mix_m<2>(w2r, w2i, xr0, xr1, acc0, acc1, c);
    mix_m<3>(w3r, w3i, xr0, xr1, acc0, acc1, c);
    mix_m<4>(w4r, w4i, xr0, xr1, acc0, acc1, c);

    __syncthreads();   // all mixing reads of s_xr complete

    // write y (scaled) back in place over xr
    {
        constexpr int LOF[25] = {0,1,1,1,2,2,2,2,2,3,3,3,3,3,3,3,4,4,4,4,4,4,4,4,4};
        #pragma unroll
        for (int r = 0; r < 25; ++r) {
            s_xr[slot * DROW + r * 32 + c]       = acc0[r] * sc0[LOF[r]];
            s_xr[(slot + 8) * DROW + r * 32 + c] = acc1[r] * sc1[LOF[r]];
        }
    }
    __syncthreads();

    // ---------------- Phase 3: back-rotate (W^T @ y) + scatter-add ----------------
    for (int s = 0; s < ET; ++s) {
        const int e = e0 + s;
        const bool valid = (e < E);
        const int ec = min(e, E - 1);
        const float* wgp = wig + (size_t)ec * WELE;
        for (int o = tid; o < WELE; o += 256) s_stage[o] = wgp[o];
        __syncthreads();
        if (valid) {
            const int dst = edst[e];
            float* op = out + (size_t)dst * DROW;
            for (int o = tid; o < DROW; o += 256) {
                const int i = o >> 5, cc = o & 31;
                float a = 0.f;
                #pragma unroll
                for (int j = 0; j < DSH; ++j)
                    a = fmaf(s_stage[j * DSH + i], s_xr[s * DROW + j * 32 + cc], a);
                atomicAdd(op + o, a);
            }
        }
        __syncthreads();
    }
}

extern "C" void kernel_launch(void* const* d_in, const int* in_sizes, int n_in,
                              void* d_out, int out_size, void* d_ws, size_t ws_size,
                              hipStream_t stream) {
    const float* x   = (const float*)d_in[0];
    const float* wig = (const float*)d_in[1];
    const float* efc = (const float*)d_in[2];
    const int*   esrc = (const int*)d_in[3];
    const int*   edst = (const int*)d_in[4];
    const float* w0  = (const float*)d_in[5];
    const float* w1r = (const float*)d_in[6];
    const float* w1i = (const float*)d_in[7];
    const float* w2r = (const float*)d_in[8];
    const float* w2i = (const float*)d_in[9];
    const float* w3r = (const float*)d_in[10];
    const float* w3i = (const float*)d_in[11];
    const float* w4r = (const float*)d_in[12];
    const float* w4i = (const float*)d_in[13];
    const float* fcw = (const float*)d_in[14];
    const float* fcb = (const float*)d_in[15];
    float* out = (float*)d_out;

    const int E = in_sizes[3];

    hipMemsetAsync(d_out, 0, (size_t)out_size * sizeof(float), stream);

    const int nblk = (E + ET - 1) / ET;
    hipLaunchKernelGGL(so2_fused_kernel, dim3(nblk), dim3(256), 0, stream,
                       x, wig, efc, esrc, edst,
                       w0, w1r, w1i, w2r, w2i, w3r, w3i, w4r, w4i,
                       fcw, fcb, out, E);
}

// Round 2
// 2725.926 us; speedup vs baseline: 1.0224x; 1.0224x over previous
//
#include <hip/hip_runtime.h>

typedef __attribute__((ext_vector_type(8))) short short8;
typedef __attribute__((ext_vector_type(4))) short short4v;
typedef __attribute__((ext_vector_type(4))) float f32x4;

#define MFMA16(a,b,c) __builtin_amdgcn_mfma_f32_16x16x32_bf16((a),(b),(c),0,0,0)

// Pre-transposed bf16 mixing weights: w0T | w1rT w1iT -w1iT | w2rT w2iT -w2iT | ...
__device__ __align__(16) short g_wt[117760];

__constant__ int c_P[5][5] = {
  {0, 2, 6, 12, 20},     // m=0: l*l+l
  {3, 7, 13, 21, 0},
  {8, 14, 22, 0, 0},
  {15, 23, 0, 0, 0},
  {24, 0, 0, 0, 0}};
__constant__ int c_Ng[5][5] = {
  {0, 2, 6, 12, 20},     // unused for m=0
  {1, 5, 11, 19, 0},
  {4, 10, 18, 0, 0},
  {9, 17, 0, 0, 0},
  {16, 0, 0, 0, 0}};
__constant__ int c_wr[5]  = {0, 25600, 74752, 102400, 114688};
__constant__ int c_wi[5]  = {0, 41984, 83968, 106496, 115712};
__constant__ int c_nwi[5] = {0, 58368, 93184, 110592, 116736};
// 50 mixing units (m, half, n-tile), heavy-first for round-robin balance
__constant__ unsigned char c_um[50] = {1,1,1,1,1,1,1,1, 1,1,1,1,1,1,1,1, 2,2,2,2,2,2, 2,2,2,2,2,2, 0,0,0,0,0,0,0,0,0,0, 3,3,3,3, 3,3,3,3, 4,4, 4,4};
__constant__ unsigned char c_uh[50] = {0,0,0,0,0,0,0,0, 1,1,1,1,1,1,1,1, 0,0,0,0,0,0, 1,1,1,1,1,1, 0,0,0,0,0,0,0,0,0,0, 0,0,0,0, 1,1,1,1, 0,0, 1,1};
__constant__ unsigned char c_ut[50] = {0,1,2,3,4,5,6,7, 0,1,2,3,4,5,6,7, 0,1,2,3,4,5, 0,1,2,3,4,5, 0,1,2,3,4,5,6,7,8,9, 0,1,2,3, 0,1,2,3, 0,1, 0,1};

__device__ __forceinline__ short f2bf(float f) {
  unsigned u = __float_as_uint(f);
  u += 0x7FFFu + ((u >> 16) & 1u);
  return (short)(u >> 16);
}

__global__ void prep_weights(const float* __restrict__ w0,
    const float* __restrict__ w1r, const float* __restrict__ w1i,
    const float* __restrict__ w2r, const float* __restrict__ w2i,
    const float* __restrict__ w3r, const float* __restrict__ w3i,
    const float* __restrict__ w4r, const float* __restrict__ w4i) {
  int idx = blockIdx.x * 256 + threadIdx.x;
  if (idx >= 117760) return;
  int off, dm; const float* src; bool neg = false;
  if (idx < 25600)       { off = 0;      dm = 160; src = w0;  }
  else if (idx < 41984)  { off = 25600;  dm = 128; src = w1r; }
  else if (idx < 58368)  { off = 41984;  dm = 128; src = w1i; }
  else if (idx < 74752)  { off = 58368;  dm = 128; src = w1i; neg = true; }
  else if (idx < 83968)  { off = 74752;  dm = 96;  src = w2r; }
  else if (idx < 93184)  { off = 83968;  dm = 96;  src = w2i; }
  else if (idx < 102400) { off = 93184;  dm = 96;  src = w2i; neg = true; }
  else if (idx < 106496) { off = 102400; dm = 64;  src = w3r; }
  else if (idx < 110592) { off = 106496; dm = 64;  src = w3i; }
  else if (idx < 114688) { off = 110592; dm = 64;  src = w3i; neg = true; }
  else if (idx < 115712) { off = 114688; dm = 32;  src = w4r; }
  else if (idx < 116736) { off = 115712; dm = 32;  src = w4i; }
  else                   { off = 116736; dm = 32;  src = w4i; neg = true; }
  int local = idx - off;
  int n = local / dm, k = local - n * dm;
  float v = src[k * dm + n];              // transpose: out[n][k] = in[k][n]
  g_wt[idx] = f2bf(neg ? -v : v);
}

// LDS (shorts): s_wig [16][32][40] @0 (20480) | s_xr [16]*1304 @20480 | s_buf(xeT/y) [16]*1304 @41344 | scale f32 [16][5][33] @62208
#define SMEM_SHORTS 67488
#define SMEM_BYTES  134976

__global__ __launch_bounds__(512) void so2_mfma_kernel(
    const float* __restrict__ x,   const float* __restrict__ wig,
    const float* __restrict__ efc, const int* __restrict__ esrc,
    const int* __restrict__ edst,  const float* __restrict__ fcw,
    const float* __restrict__ fcb, float* __restrict__ out, int E)
{
  extern __shared__ short smem[];
  short* s_wig = smem;
  short* s_xr  = smem + 20480;
  short* s_buf = smem + 41344;            // xe^T in fwd, then y
  float* s_sc  = (float*)(smem + 62208);

  const int tid  = threadIdx.x;
  const int lane = tid & 63;
  const int wid  = tid >> 6;
  const int l15  = lane & 15;
  const int lg   = lane >> 4;
  const int e0   = blockIdx.x * 16;

  // ---- (a) zero pad-sensitive buffers (K-pads must be 0, not garbage) ----
  {
    int* z1 = (int*)s_wig;
    for (int o = tid; o < 10240; o += 512) z1[o] = 0;
    int* z2 = (int*)s_buf;
    for (int o = tid; o < 10432; o += 512) z2[o] = 0;
  }
  __syncthreads();

  // ---- (b) stage xe^T bf16, wigner bf16, compute silu scale ----
  for (int o = tid; o < 12800; o += 512) {
    int e = o / 800, q = o - e * 800;
    int ge = e0 + e; if (ge >= E) ge = E - 1;
    int coeff = q >> 5, ch = q & 31;
    float v = x[(size_t)esrc[ge] * 800 + q];
    s_buf[e * 1304 + ch * 40 + coeff] = f2bf(v);
  }
  for (int o = tid; o < 10000; o += 512) {
    int e = o / 625, q = o - e * 625;
    int ge = e0 + e; if (ge >= E) ge = E - 1;
    int i = q / 25, j = q - i * 25;
    s_wig[e * 1280 + i * 40 + j] = f2bf(wig[(size_t)ge * 625 + q]);
  }
  for (int o = tid; o < 2560; o += 512) {
    int e = o / 160, q = o - e * 160;
    int ge = e0 + e; if (ge >= E) ge = E - 1;
    int l = q >> 5, co = q & 31;
    const float* f = efc + (size_t)ge * 64;
    float a = fcb[q];
    #pragma unroll 8
    for (int k = 0; k < 64; ++k) a = fmaf(f[k], fcw[k * 160 + q], a);
    s_sc[e * 165 + l * 33 + co] = a / (1.f + __expf(-a));
  }
  __syncthreads();

  // ---- (c) forward rotation: xr^T = xe^T @ W^T (2 edges per wave) ----
  #pragma unroll
  for (int i = 0; i < 2; ++i) {
    const int e = wid * 2 + i;
    const short* xeb = s_buf + e * 1304;
    const short* wgb = s_wig + e * 1280;
    short8 a0 = *(const short8*)(xeb + l15 * 40 + lg * 8);          // ch 0-15
    short8 a1 = *(const short8*)(xeb + (16 + l15) * 40 + lg * 8);   // ch 16-31
    short8 b0 = *(const short8*)(wgb + l15 * 40 + lg * 8);          // coeff_out 0-15
    short8 b1 = *(const short8*)(wgb + (16 + l15) * 40 + lg * 8);   // coeff_out 16-31
    f32x4 d00 = {0.f,0.f,0.f,0.f}, d01 = {0.f,0.f,0.f,0.f};
    f32x4 d10 = {0.f,0.f,0.f,0.f}, d11 = {0.f,0.f,0.f,0.f};
    d00 = MFMA16(a0, b0, d00);
    d01 = MFMA16(a0, b1, d01);
    d10 = MFMA16(a1, b0, d10);
    d11 = MFMA16(a1, b1, d11);
    short* xrb = s_xr + e * 1304;
    short4v v;
    v[0]=f2bf(d00[0]); v[1]=f2bf(d00[1]); v[2]=f2bf(d00[2]); v[3]=f2bf(d00[3]);
    *(short4v*)(xrb + l15 * 40 + lg * 4) = v;
    v[0]=f2bf(d10[0]); v[1]=f2bf(d10[1]); v[2]=f2bf(d10[2]); v[3]=f2bf(d10[3]);
    *(short4v*)(xrb + l15 * 40 + 16 + lg * 4) = v;
    v[0]=f2bf(d01[0]); v[1]=f2bf(d01[1]); v[2]=f2bf(d01[2]); v[3]=f2bf(d01[3]);
    *(short4v*)(xrb + (16 + l15) * 40 + lg * 4) = v;
    v[0]=f2bf(d11[0]); v[1]=f2bf(d11[1]); v[2]=f2bf(d11[2]); v[3]=f2bf(d11[3]);
    *(short4v*)(xrb + (16 + l15) * 40 + 16 + lg * 4) = v;
  }
  __syncthreads();

  // ---- (d) zero y pad-rows (aliased by xe^T), then SO(2) mixing ----
  for (int o = tid; o < 1792; o += 512) {
    int e = o / 112, q = o - e * 112;
    int k = 25 + (q >> 4), cp = q & 15;
    ((int*)s_buf)[e * 652 + k * 20 + cp] = 0;
  }
  for (int u = wid; u < 50; u += 8) {
    const int m = c_um[u], h = c_uh[u], t = c_ut[u];
    const int col  = t * 16 + l15;
    const int koff = lg * 8;
    const short* xrl = s_xr + l15 * 1304 + koff;   // row = edge = l15
    f32x4 acc = {0.f,0.f,0.f,0.f};
    if (m == 0) {
      const short* B = g_wt + col * 160 + koff;
      #pragma unroll 5
      for (int ks = 0; ks < 5; ++ks) {
        short8 a = *(const short8*)(xrl + c_P[0][ks] * 40);
        short8 b = *(const short8*)(B + ks * 32);
        acc = MFMA16(a, b, acc);
      }
    } else {
      const int dm = (5 - m) * 32;
      const int lm = 5 - m;
      const short* B1 = g_wt + (h == 0 ? c_wr[m]  : c_wi[m]) + col * dm + koff;
      const short* B2 = g_wt + (h == 0 ? c_nwi[m] : c_wr[m]) + col * dm + koff;
      #pragma unroll 4
      for (int ks = 0; ks < 4; ++ks) if (ks < lm) {
        short8 ap = *(const short8*)(xrl + c_P[m][ks] * 40);
        short8 b1 = *(const short8*)(B1 + ks * 32);
        acc = MFMA16(ap, b1, acc);
        short8 an = *(const short8*)(xrl + c_Ng[m][ks] * 40);
        short8 b2 = *(const short8*)(B2 + ks * 32);
        acc = MFMA16(an, b2, acc);
      }
    }
    const int lo = col >> 5, co = col & 31;
    const int coeff = (h == 0) ? c_P[m][lo] : c_Ng[m][lo];
    const int lsc = m + lo;
    #pragma unroll 4
    for (int r = 0; r < 4; ++r) {
      const int e = lg * 4 + r;
      float sc = s_sc[e * 165 + lsc * 33 + co];
      s_buf[e * 1304 + coeff * 40 + co] = f2bf(acc[r] * sc);
    }
  }
  __syncthreads();

  // ---- (e) back-rotation: yb^T = y^T @ W, then scatter-add ----
  #pragma unroll
  for (int i = 0; i < 2; ++i) {
    const int e  = wid * 2 + i;
    const int ge = e0 + e;
    const short* yb  = s_buf + e * 1304 + lg * 8 * 40;
    const short* wgb = s_wig + e * 1280 + lg * 8 * 40;
    short8 a0, a1, b0, b1;
    #pragma unroll 8
    for (int j = 0; j < 8; ++j) {
      a0[j] = yb[j * 40 + l15];            // y[k][ch=l15]
      a1[j] = yb[j * 40 + 16 + l15];       // y[k][ch=16+l15]
      b0[j] = wgb[j * 40 + l15];           // W[k][coeff=l15]
      b1[j] = wgb[j * 40 + 16 + l15];      // W[k][coeff=16+l15]
    }
    f32x4 d00 = {0.f,0.f,0.f,0.f}, d01 = {0.f,0.f,0.f,0.f};
    f32x4 d10 = {0.f,0.f,0.f,0.f}, d11 = {0.f,0.f,0.f,0.f};
    d00 = MFMA16(a0, b0, d00);
    d01 = MFMA16(a0, b1, d01);
    d10 = MFMA16(a1, b0, d10);
    d11 = MFMA16(a1, b1, d11);
    if (ge < E) {
      float* op = out + (size_t)edst[ge] * 800;
      const int chb = lg * 4;
      #pragma unroll 4
      for (int r = 0; r < 4; ++r) {
        atomicAdd(op + l15 * 32 + chb + r,       d00[r]);
        atomicAdd(op + l15 * 32 + 16 + chb + r,  d10[r]);
      }
      if (l15 < 9) {
        #pragma unroll 4
        for (int r = 0; r < 4; ++r) {
          atomicAdd(op + (16 + l15) * 32 + chb + r,      d01[r]);
          atomicAdd(op + (16 + l15) * 32 + 16 + chb + r, d11[r]);
        }
      }
    }
  }
}

extern "C" void kernel_launch(void* const* d_in, const int* in_sizes, int n_in,
                              void* d_out, int out_size, void* d_ws, size_t ws_size,
                              hipStream_t stream) {
  const float* x    = (const float*)d_in[0];
  const float* wigp = (const float*)d_in[1];
  const float* efc  = (const float*)d_in[2];
  const int*   esrc = (const int*)d_in[3];
  const int*   edst = (const int*)d_in[4];
  const float* w0   = (const float*)d_in[5];
  const float* w1r  = (const float*)d_in[6];
  const float* w1i  = (const float*)d_in[7];
  const float* w2r  = (const float*)d_in[8];
  const float* w2i  = (const float*)d_in[9];
  const float* w3r  = (const float*)d_in[10];
  const float* w3i  = (const float*)d_in[11];
  const float* w4r  = (const float*)d_in[12];
  const float* w4i  = (const float*)d_in[13];
  const float* fcw  = (const float*)d_in[14];
  const float* fcb  = (const float*)d_in[15];
  float* out = (float*)d_out;
  const int E = in_sizes[3];

  hipFuncSetAttribute((const void*)so2_mfma_kernel,
                      hipFuncAttributeMaxDynamicSharedMemorySize, SMEM_BYTES);

  prep_weights<<<(117760 + 255) / 256, 256, 0, stream>>>(
      w0, w1r, w1i, w2r, w2i, w3r, w3i, w4r, w4i);

  hipMemsetAsync(d_out, 0, (size_t)out_size * sizeof(float), stream);

  const int nblk = (E + 15) / 16;
  so2_mfma_kernel<<<nblk, 512, SMEM_BYTES, stream>>>(
      x, wigp, efc, esrc, edst, fcw, fcb, out, E);
}

// Round 3
// 2126.451 us; speedup vs baseline: 1.3107x; 1.2819x over previous
//
#include <hip/hip_runtime.h>

typedef __attribute__((ext_vector_type(8))) short short8;
typedef __attribute__((ext_vector_type(4))) short short4v;
typedef __attribute__((ext_vector_type(4))) float f32x4;

#define MFMA16(a,b,c) __builtin_amdgcn_mfma_f32_16x16x32_bf16((a),(b),(c),0,0,0)

// Pre-transposed bf16 mixing weights: w0T | w1rT w1iT -w1iT | w2rT w2iT -w2iT | ...
__device__ __align__(16) short g_wt[117760];

__constant__ int c_P[5][5] = {
  {0, 2, 6, 12, 20},
  {3, 7, 13, 21, 0},
  {8, 14, 22, 0, 0},
  {15, 23, 0, 0, 0},
  {24, 0, 0, 0, 0}};
__constant__ int c_Ng[5][5] = {
  {0, 2, 6, 12, 20},
  {1, 5, 11, 19, 0},
  {4, 10, 18, 0, 0},
  {9, 17, 0, 0, 0},
  {16, 0, 0, 0, 0}};
__constant__ int c_wr[5]  = {0, 25600, 74752, 102400, 114688};
__constant__ int c_wi[5]  = {0, 41984, 83968, 106496, 115712};
__constant__ int c_nwi[5] = {0, 58368, 93184, 110592, 116736};
// 50 mixing units (m, half, n-tile)
__constant__ unsigned char c_um[50] = {1,1,1,1,1,1,1,1, 1,1,1,1,1,1,1,1, 2,2,2,2,2,2, 2,2,2,2,2,2, 0,0,0,0,0,0,0,0,0,0, 3,3,3,3, 3,3,3,3, 4,4, 4,4};
__constant__ unsigned char c_uh[50] = {0,0,0,0,0,0,0,0, 1,1,1,1,1,1,1,1, 0,0,0,0,0,0, 1,1,1,1,1,1, 0,0,0,0,0,0,0,0,0,0, 0,0,0,0, 1,1,1,1, 0,0, 1,1};
__constant__ unsigned char c_ut[50] = {0,1,2,3,4,5,6,7, 0,1,2,3,4,5,6,7, 0,1,2,3,4,5, 0,1,2,3,4,5, 0,1,2,3,4,5,6,7,8,9, 0,1,2,3, 0,1,2,3, 0,1, 0,1};

__device__ __forceinline__ short f2bf(float f) {
  unsigned u = __float_as_uint(f);
  u += 0x7FFFu + ((u >> 16) & 1u);
  return (short)(u >> 16);
}

__global__ void prep_weights(const float* __restrict__ w0,
    const float* __restrict__ w1r, const float* __restrict__ w1i,
    const float* __restrict__ w2r, const float* __restrict__ w2i,
    const float* __restrict__ w3r, const float* __restrict__ w3i,
    const float* __restrict__ w4r, const float* __restrict__ w4i) {
  int idx = blockIdx.x * 256 + threadIdx.x;
  if (idx >= 117760) return;
  int off, dm; const float* src; bool neg = false;
  if (idx < 25600)       { off = 0;      dm = 160; src = w0;  }
  else if (idx < 41984)  { off = 25600;  dm = 128; src = w1r; }
  else if (idx < 58368)  { off = 41984;  dm = 128; src = w1i; }
  else if (idx < 74752)  { off = 58368;  dm = 128; src = w1i; neg = true; }
  else if (idx < 83968)  { off = 74752;  dm = 96;  src = w2r; }
  else if (idx < 93184)  { off = 83968;  dm = 96;  src = w2i; }
  else if (idx < 102400) { off = 93184;  dm = 96;  src = w2i; neg = true; }
  else if (idx < 106496) { off = 102400; dm = 64;  src = w3r; }
  else if (idx < 110592) { off = 106496; dm = 64;  src = w3i; }
  else if (idx < 114688) { off = 110592; dm = 64;  src = w3i; neg = true; }
  else if (idx < 115712) { off = 114688; dm = 32;  src = w4r; }
  else if (idx < 116736) { off = 115712; dm = 32;  src = w4i; }
  else                   { off = 116736; dm = 32;  src = w4i; neg = true; }
  int local = idx - off;
  int n = local / dm, k = local - n * dm;
  float v = src[k * dm + n];
  g_wt[idx] = f2bf(neg ? -v : v);
}

// ---------------- counting sort of edges by dst ----------------
__global__ void hist_kernel(const int* __restrict__ edst, int* __restrict__ cnt, int E) {
  int i = blockIdx.x * 256 + threadIdx.x;
  if (i < E) atomicAdd(&cnt[edst[i]], 1);
}

__global__ __launch_bounds__(1024) void scan_kernel(
    const int* __restrict__ cnt, int* __restrict__ cursor, int N) {
  __shared__ int s[1024];
  const int t = threadIdx.x;
  int carry = 0;
  for (int base = 0; base < N; base += 1024) {
    int i = base + t;
    int v = (i < N) ? cnt[i] : 0;
    s[t] = v;
    __syncthreads();
    int acc = v;
    for (int d = 1; d < 1024; d <<= 1) {
      int add = (t >= d) ? s[t - d] : 0;
      __syncthreads();
      acc += add;
      s[t] = acc;
      __syncthreads();
    }
    if (i < N) cursor[i] = carry + acc - v;
    carry += s[1023];
    __syncthreads();
  }
}

__global__ void scatter_kernel(const int* __restrict__ edst, int* __restrict__ cursor,
                               int* __restrict__ order, int E) {
  int i = blockIdx.x * 256 + threadIdx.x;
  if (i < E) {
    int p = atomicAdd(&cursor[edst[i]], 1);
    order[p] = i;
  }
}

// ---------------- main fused kernel: 8 sorted edges / 256-thread block ----------------
// LDS shorts: s_wig [8][32][40] @0 | s_xr 9*1304 @10240 | s_buf 8*1304 @21976 |
//             s_sc f32 [8][165] @32408 | meta ints @35048 | yb f32 overlay @10240
#define SMEM_BYTES 70336

__global__ __launch_bounds__(256, 2) void so2_mfma_kernel(
    const float* __restrict__ x,   const float* __restrict__ wig,
    const float* __restrict__ efc, const int* __restrict__ esrc,
    const int* __restrict__ edst,  const float* __restrict__ fcw,
    const float* __restrict__ fcb, const int* __restrict__ cnt,
    const int* __restrict__ order, float* __restrict__ out, int E)
{
  extern __shared__ short smem[];
  short* s_wig = smem;
  short* s_xr  = smem + 10240;
  short* s_buf = smem + 21976;
  float* s_sc  = (float*)(smem + 32408);
  int*   s_meta = (int*)(smem + 35048); // [0..7] eid [8..15] src [16..23] dst [24] ng [25..32] gdst [33..40] gs [41..48] ge [49..56] gown
  float* yb_s  = (float*)(smem + 10240);

  const int tid  = threadIdx.x;
  const int lane = tid & 63;
  const int wid  = tid >> 6;
  const int l15  = lane & 15;
  const int lg   = lane >> 4;
  const int e0   = blockIdx.x * 8;

  // ---- (a) zero pads + load edge meta ----
  for (int o = tid; o < 10988; o += 256) {
    if (o < 5120)       ((int*)smem)[o] = 0;                 // s_wig
    else if (o < 10336) ((int*)(smem + 21976))[o - 5120] = 0; // s_buf
    else                ((int*)(smem + 20672))[o - 10336] = 0; // s_xr zero-row 8
  }
  if (tid < 8) {
    int idx = e0 + tid;
    int og = (idx < E) ? order[idx] : -1;
    s_meta[tid]      = (og >= 0) ? og : 0;
    s_meta[8 + tid]  = (og >= 0) ? esrc[og] : 0;
    s_meta[16 + tid] = (og >= 0) ? edst[og] : -1;
  }
  __syncthreads();

  // ---- (b) stage xe^T, wigner (bf16), silu scales; thread 0 builds dst groups ----
  if (tid == 0) {
    int ng = 0, j = 0;
    while (j < 8) {
      int d = s_meta[16 + j];
      if (d < 0) break;
      int k = j + 1;
      while (k < 8 && s_meta[16 + k] == d) ++k;
      s_meta[25 + ng] = d;
      s_meta[33 + ng] = j;
      s_meta[41 + ng] = k;
      s_meta[49 + ng] = ((k - j) == cnt[d]) ? 1 : 0;
      ++ng; j = k;
    }
    s_meta[24] = ng;
  }
  for (int o = tid; o < 6400; o += 256) {
    int e = o / 800, q = o - e * 800;
    const float* xp = x + (size_t)s_meta[8 + e] * 800;
    int coeff = q >> 5, ch = q & 31;
    s_buf[e * 1304 + ch * 40 + coeff] = f2bf(xp[q]);
  }
  for (int o = tid; o < 5000; o += 256) {
    int e = o / 625, q = o - e * 625;
    int i = q / 25, j = q - i * 25;
    s_wig[e * 1280 + i * 40 + j] = f2bf(wig[(size_t)s_meta[e] * 625 + q]);
  }
  for (int o = tid; o < 1280; o += 256) {
    int e = o / 160, q = o - e * 160;
    const float* f = efc + (size_t)s_meta[e] * 64;
    float a = fcb[q];
    #pragma unroll 8
    for (int k = 0; k < 64; ++k) a = fmaf(f[k], fcw[k * 160 + q], a);
    s_sc[e * 165 + (q >> 5) * 33 + (q & 31)] = a / (1.f + __expf(-a));
  }
  __syncthreads();

  // ---- (c) forward rotation: xr = W @ xe  (2 edges per wave) ----
  #pragma unroll
  for (int i = 0; i < 2; ++i) {
    const int e = wid * 2 + i;
    const short* xeb = s_buf + e * 1304;
    const short* wgb = s_wig + e * 1280;
    short8 a0 = *(const short8*)(xeb + l15 * 40 + lg * 8);
    short8 a1 = *(const short8*)(xeb + (16 + l15) * 40 + lg * 8);
    short8 b0 = *(const short8*)(wgb + l15 * 40 + lg * 8);
    short8 b1 = *(const short8*)(wgb + (16 + l15) * 40 + lg * 8);
    f32x4 d00 = {0.f,0.f,0.f,0.f}, d01 = {0.f,0.f,0.f,0.f};
    f32x4 d10 = {0.f,0.f,0.f,0.f}, d11 = {0.f,0.f,0.f,0.f};
    d00 = MFMA16(a0, b0, d00);
    d01 = MFMA16(a0, b1, d01);
    d10 = MFMA16(a1, b0, d10);
    d11 = MFMA16(a1, b1, d11);
    short* xrb = s_xr + e * 1304;
    short4v v;
    v[0]=f2bf(d00[0]); v[1]=f2bf(d00[1]); v[2]=f2bf(d00[2]); v[3]=f2bf(d00[3]);
    *(short4v*)(xrb + l15 * 40 + lg * 4) = v;
    v[0]=f2bf(d10[0]); v[1]=f2bf(d10[1]); v[2]=f2bf(d10[2]); v[3]=f2bf(d10[3]);
    *(short4v*)(xrb + l15 * 40 + 16 + lg * 4) = v;
    v[0]=f2bf(d01[0]); v[1]=f2bf(d01[1]); v[2]=f2bf(d01[2]); v[3]=f2bf(d01[3]);
    *(short4v*)(xrb + (16 + l15) * 40 + lg * 4) = v;
    v[0]=f2bf(d11[0]); v[1]=f2bf(d11[1]); v[2]=f2bf(d11[2]); v[3]=f2bf(d11[3]);
    *(short4v*)(xrb + (16 + l15) * 40 + 16 + lg * 4) = v;
  }
  __syncthreads();

  // ---- (d) zero y K-pad rows, SO(2) mixing (M=16 rows, edges 0-7 + zero row) ----
  for (int o = tid; o < 1120; o += 256) {
    int e = o / 140, q = o - e * 140;
    int k = 25 + (q / 20), cp = q % 20;
    ((int*)s_buf)[e * 652 + k * 20 + cp] = 0;
  }
  const int ez = (l15 < 8) ? l15 : 8;
  for (int u = wid; u < 50; u += 4) {
    const int m = c_um[u], h = c_uh[u], t = c_ut[u];
    const int col  = t * 16 + l15;
    const int koff = lg * 8;
    const short* xrl = s_xr + ez * 1304 + koff;
    f32x4 acc = {0.f,0.f,0.f,0.f};
    if (m == 0) {
      const short* B = g_wt + col * 160 + koff;
      #pragma unroll 5
      for (int ks = 0; ks < 5; ++ks) {
        short8 a = *(const short8*)(xrl + c_P[0][ks] * 40);
        short8 b = *(const short8*)(B + ks * 32);
        acc = MFMA16(a, b, acc);
      }
    } else {
      const int dm = (5 - m) * 32;
      const int lm = 5 - m;
      const short* B1 = g_wt + (h == 0 ? c_wr[m]  : c_wi[m]) + col * dm + koff;
      const short* B2 = g_wt + (h == 0 ? c_nwi[m] : c_wr[m]) + col * dm + koff;
      #pragma unroll 4
      for (int ks = 0; ks < 4; ++ks) if (ks < lm) {
        short8 ap = *(const short8*)(xrl + c_P[m][ks] * 40);
        short8 b1 = *(const short8*)(B1 + ks * 32);
        acc = MFMA16(ap, b1, acc);
        short8 an = *(const short8*)(xrl + c_Ng[m][ks] * 40);
        short8 b2 = *(const short8*)(B2 + ks * 32);
        acc = MFMA16(an, b2, acc);
      }
    }
    const int lo = col >> 5, co = col & 31;
    const int coeff = (h == 0) ? c_P[m][lo] : c_Ng[m][lo];
    const int lsc = m + lo;
    #pragma unroll 4
    for (int r = 0; r < 4; ++r) {
      const int e = lg * 4 + r;
      if (e < 8) {
        float sc = s_sc[e * 165 + lsc * 33 + co];
        s_buf[e * 1304 + coeff * 40 + co] = f2bf(acc[r] * sc);
      }
    }
  }
  __syncthreads();

  // ---- (e) back-rotation: yb = W^T @ y (2 edges per wave), keep in regs ----
  f32x4 r00[2], r01[2], r10[2], r11[2];
  #pragma unroll
  for (int i = 0; i < 2; ++i) {
    const int e = wid * 2 + i;
    const short* yb  = s_buf + e * 1304 + lg * 8 * 40;
    const short* wgb = s_wig + e * 1280 + lg * 8 * 40;
    short8 a0, a1, b0, b1;
    #pragma unroll 8
    for (int j = 0; j < 8; ++j) {
      a0[j] = yb[j * 40 + l15];
      a1[j] = yb[j * 40 + 16 + l15];
      b0[j] = wgb[j * 40 + l15];
      b1[j] = wgb[j * 40 + 16 + l15];
    }
    f32x4 d00 = {0.f,0.f,0.f,0.f}, d01 = {0.f,0.f,0.f,0.f};
    f32x4 d10 = {0.f,0.f,0.f,0.f}, d11 = {0.f,0.f,0.f,0.f};
    d00 = MFMA16(a0, b0, d00);
    d01 = MFMA16(a0, b1, d01);
    d10 = MFMA16(a1, b0, d10);
    d11 = MFMA16(a1, b1, d11);
    r00[i] = d00; r01[i] = d01; r10[i] = d10; r11[i] = d11;
  }
  __syncthreads();   // all LDS reads done before yb_s overlay writes

  #pragma unroll
  for (int i = 0; i < 2; ++i) {
    const int e = wid * 2 + i;
    float* yb = yb_s + e * 840;
    #pragma unroll 4
    for (int r = 0; r < 4; ++r) {
      yb[l15 * 33 + lg * 4 + r]      = r00[i][r];
      yb[l15 * 33 + 16 + lg * 4 + r] = r10[i][r];
    }
    if (l15 < 9) {
      #pragma unroll 4
      for (int r = 0; r < 4; ++r) {
        yb[(16 + l15) * 33 + lg * 4 + r]      = r01[i][r];
        yb[(16 + l15) * 33 + 16 + lg * 4 + r] = r11[i][r];
      }
    }
  }
  __syncthreads();

  // ---- (f) segmented flush: one add per (dst-group, element) ----
  const int ng = s_meta[24];
  for (int o = tid; o < 800; o += 256) {
    const int yoff = (o >> 5) * 33 + (o & 31);
    for (int g = 0; g < ng; ++g) {
      float sum = 0.f;
      const int gs = s_meta[33 + g], ge = s_meta[41 + g];
      for (int e = gs; e < ge; ++e) sum += yb_s[e * 840 + yoff];
      float* ad = out + (size_t)s_meta[25 + g] * 800 + o;
      if (s_meta[49 + g]) *ad = sum;
      else atomicAdd(ad, sum);
    }
  }
}

extern "C" void kernel_launch(void* const* d_in, const int* in_sizes, int n_in,
                              void* d_out, int out_size, void* d_ws, size_t ws_size,
                              hipStream_t stream) {
  const float* x    = (const float*)d_in[0];
  const float* wigp = (const float*)d_in[1];
  const float* efc  = (const float*)d_in[2];
  const int*   esrc = (const int*)d_in[3];
  const int*   edst = (const int*)d_in[4];
  const float* w0   = (const float*)d_in[5];
  const float* w1r  = (const float*)d_in[6];
  const float* w1i  = (const float*)d_in[7];
  const float* w2r  = (const float*)d_in[8];
  const float* w2i  = (const float*)d_in[9];
  const float* w3r  = (const float*)d_in[10];
  const float* w3i  = (const float*)d_in[11];
  const float* w4r  = (const float*)d_in[12];
  const float* w4i  = (const float*)d_in[13];
  const float* fcw  = (const float*)d_in[14];
  const float* fcb  = (const float*)d_in[15];
  float* out = (float*)d_out;
  const int E = in_sizes[3];
  const int N = out_size / 800;

  int* cnt    = (int*)d_ws;        // [N] degree histogram
  int* cursor = cnt + N;           // [N] scatter cursors (exclusive prefix)
  int* order  = cnt + 2 * N;       // [E] edge ids sorted by dst

  hipFuncSetAttribute((const void*)so2_mfma_kernel,
                      hipFuncAttributeMaxDynamicSharedMemorySize, SMEM_BYTES);

  prep_weights<<<(117760 + 255) / 256, 256, 0, stream>>>(
      w0, w1r, w1i, w2r, w2i, w3r, w3i, w4r, w4i);

  hipMemsetAsync(d_out, 0, (size_t)out_size * sizeof(float), stream);
  hipMemsetAsync(cnt, 0, (size_t)N * sizeof(int), stream);

  hist_kernel<<<(E + 255) / 256, 256, 0, stream>>>(edst, cnt, E);
  scan_kernel<<<1, 1024, 0, stream>>>(cnt, cursor, N);
  scatter_kernel<<<(E + 255) / 256, 256, 0, stream>>>(edst, cursor, order, E);

  const int nblk = (E + 7) / 8;
  so2_mfma_kernel<<<nblk, 256, SMEM_BYTES, stream>>>(
      x, wigp, efc, esrc, edst, fcw, fcb, cnt, order, out, E);
}

// Round 4
// 2084.334 us; speedup vs baseline: 1.3371x; 1.0202x over previous
//
#include <hip/hip_runtime.h>

typedef __attribute__((ext_vector_type(8))) short short8;
typedef __attribute__((ext_vector_type(4))) short short4v;
typedef __attribute__((ext_vector_type(4))) float f32x4;

#define MFMA16(a,b,c) __builtin_amdgcn_mfma_f32_16x16x32_bf16((a),(b),(c),0,0,0)

// Pre-transposed bf16 mixing weights: w0T | w1rT w1iT -w1iT | ... | w4iT -w4iT
__device__ __align__(16) short g_wt[117760];
// Pre-transposed bf16 radial weights fcwT[160][64]
__device__ __align__(16) short g_fcwt[10240];

__constant__ int c_P[5][5] = {
  {0, 2, 6, 12, 20},
  {3, 7, 13, 21, 0},
  {8, 14, 22, 0, 0},
  {15, 23, 0, 0, 0},
  {24, 0, 0, 0, 0}};
__constant__ int c_Ng[5][5] = {
  {0, 2, 6, 12, 20},
  {1, 5, 11, 19, 0},
  {4, 10, 18, 0, 0},
  {9, 17, 0, 0, 0},
  {16, 0, 0, 0, 0}};
__constant__ int c_wr[5]  = {0, 25600, 74752, 102400, 114688};
__constant__ int c_wi[5]  = {0, 41984, 83968, 106496, 115712};
__constant__ int c_nwi[5] = {0, 58368, 93184, 110592, 116736};
__constant__ unsigned char c_um[50] = {1,1,1,1,1,1,1,1, 1,1,1,1,1,1,1,1, 2,2,2,2,2,2, 2,2,2,2,2,2, 0,0,0,0,0,0,0,0,0,0, 3,3,3,3, 3,3,3,3, 4,4, 4,4};
__constant__ unsigned char c_uh[50] = {0,0,0,0,0,0,0,0, 1,1,1,1,1,1,1,1, 0,0,0,0,0,0, 1,1,1,1,1,1, 0,0,0,0,0,0,0,0,0,0, 0,0,0,0, 1,1,1,1, 0,0, 1,1};
__constant__ unsigned char c_ut[50] = {0,1,2,3,4,5,6,7, 0,1,2,3,4,5,6,7, 0,1,2,3,4,5, 0,1,2,3,4,5, 0,1,2,3,4,5,6,7,8,9, 0,1,2,3, 0,1,2,3, 0,1, 0,1};

__device__ __forceinline__ short f2bf(float f) {
  unsigned u = __float_as_uint(f);
  u += 0x7FFFu + ((u >> 16) & 1u);
  return (short)(u >> 16);
}

__global__ void prep_weights(const float* __restrict__ w0,
    const float* __restrict__ w1r, const float* __restrict__ w1i,
    const float* __restrict__ w2r, const float* __restrict__ w2i,
    const float* __restrict__ w3r, const float* __restrict__ w3i,
    const float* __restrict__ w4r, const float* __restrict__ w4i,
    const float* __restrict__ fcw) {
  int idx = blockIdx.x * 256 + threadIdx.x;
  if (idx >= 128000) return;
  if (idx >= 117760) {                         // fcwT[n][k] = fcw[k][n]
    int local = idx - 117760;
    int n = local >> 6, k = local & 63;
    g_fcwt[local] = f2bf(fcw[k * 160 + n]);
    return;
  }
  int off, dm; const float* src; bool neg = false;
  if (idx < 25600)       { off = 0;      dm = 160; src = w0;  }
  else if (idx < 41984)  { off = 25600;  dm = 128; src = w1r; }
  else if (idx < 58368)  { off = 41984;  dm = 128; src = w1i; }
  else if (idx < 74752)  { off = 58368;  dm = 128; src = w1i; neg = true; }
  else if (idx < 83968)  { off = 74752;  dm = 96;  src = w2r; }
  else if (idx < 93184)  { off = 83968;  dm = 96;  src = w2i; }
  else if (idx < 102400) { off = 93184;  dm = 96;  src = w2i; neg = true; }
  else if (idx < 106496) { off = 102400; dm = 64;  src = w3r; }
  else if (idx < 110592) { off = 106496; dm = 64;  src = w3i; }
  else if (idx < 114688) { off = 110592; dm = 64;  src = w3i; neg = true; }
  else if (idx < 115712) { off = 114688; dm = 32;  src = w4r; }
  else if (idx < 116736) { off = 115712; dm = 32;  src = w4i; }
  else                   { off = 116736; dm = 32;  src = w4i; neg = true; }
  int local = idx - off;
  int n = local / dm, k = local - n * dm;
  float v = src[k * dm + n];
  g_wt[idx] = f2bf(neg ? -v : v);
}

// ---------------- counting sort of edges by dst ----------------
__global__ void hist_kernel(const int* __restrict__ edst, int* __restrict__ cnt, int E) {
  int i = blockIdx.x * 256 + threadIdx.x;
  if (i < E) atomicAdd(&cnt[edst[i]], 1);
}

__global__ __launch_bounds__(1024) void scan_kernel(
    const int* __restrict__ cnt, int* __restrict__ cursor, int N) {
  __shared__ int s[1024];
  const int t = threadIdx.x;
  int carry = 0;
  for (int base = 0; base < N; base += 1024) {
    int i = base + t;
    int v = (i < N) ? cnt[i] : 0;
    s[t] = v;
    __syncthreads();
    int acc = v;
    for (int d = 1; d < 1024; d <<= 1) {
      int add = (t >= d) ? s[t - d] : 0;
      __syncthreads();
      acc += add;
      s[t] = acc;
      __syncthreads();
    }
    if (i < N) cursor[i] = carry + acc - v;
    carry += s[1023];
    __syncthreads();
  }
}

__global__ void scatter_kernel(const int* __restrict__ edst, int* __restrict__ cursor,
                               int* __restrict__ order, int E) {
  int i = blockIdx.x * 256 + threadIdx.x;
  if (i < E) {
    int p = atomicAdd(&cursor[edst[i]], 1);
    order[p] = i;
  }
}

// ---------------- persistent fused kernel: 8 sorted edges / tile ----------------
// LDS shorts: s_wig [8][32][40] @0 | s_xr 9*1304 @10240 | s_buf 8*1304 @21976 |
//   s_sc f32 [8][165] @32408 | s_meta int[2][64] @35048 | yb f32 overlay @10240
#define SMEM_BYTES 70656
#define NBLK 512

__device__ __forceinline__ void do_prefetch(
    const int* __restrict__ mb,
    const float* __restrict__ x, const float* __restrict__ wig,
    const float* __restrict__ efc,
    int tid, int l15, int lg,
    float* __restrict__ xv, float* __restrict__ wv, float* __restrict__ ev)
{
  #pragma unroll
  for (int i = 0; i < 25; ++i) {
    int o = tid + i * 256;
    int e = o / 800, q = o - e * 800;
    xv[i] = x[(size_t)mb[8 + e] * 800 + q];
  }
  #pragma unroll
  for (int i = 0; i < 20; ++i) {
    int o = tid + i * 256;
    if (o < 5000) {
      int e = o / 625, q = o - e * 625;
      wv[i] = wig[(size_t)mb[e] * 625 + q];
    }
  }
  const int oge = mb[l15 < 8 ? l15 : 7];
  const float* ep = efc + (size_t)oge * 64 + lg * 8;
  *(float4*)(ev + 0)  = *(const float4*)(ep + 0);
  *(float4*)(ev + 4)  = *(const float4*)(ep + 4);
  *(float4*)(ev + 8)  = *(const float4*)(ep + 32);
  *(float4*)(ev + 12) = *(const float4*)(ep + 36);
}

__global__ __launch_bounds__(256, 2) void so2_mfma_kernel(
    const float* __restrict__ x,   const float* __restrict__ wig,
    const float* __restrict__ efc, const int* __restrict__ esrc,
    const int* __restrict__ edst,  const float* __restrict__ fcb,
    const int* __restrict__ cnt,   const int* __restrict__ order,
    float* __restrict__ out, int E)
{
  extern __shared__ short smem[];
  short* s_wig = smem;
  short* s_xr  = smem + 10240;
  short* s_buf = smem + 21976;
  float* s_sc  = (float*)(smem + 32408);
  int (*s_meta)[64] = (int(*)[64])(smem + 35048);
  float* yb_s  = (float*)(smem + 10240);

  const int tid  = threadIdx.x;
  const int lane = tid & 63;
  const int wid  = tid >> 6;
  const int l15  = lane & 15;
  const int lg   = lane >> 4;

  const int T_total = (E + 7) / 8;
  const int TPB = (T_total + NBLK - 1) / NBLK;
  const int t0 = blockIdx.x * TPB;
  const int t_end = min(t0 + TPB, T_total);
  if (t0 >= t_end) return;

  // ---------------- one-time zero init ----------------
  for (int o = tid; o < 5120; o += 256) ((int*)s_wig)[o] = 0;
  for (int o = tid; o < 5216; o += 256) ((int*)(s_buf))[o] = 0;
  for (int o = tid; o < 652;  o += 256) ((int*)(s_xr + 8 * 1304))[o] = 0;

  // ---------------- prologue: meta(t0) + issue meta(t0+1) ----------------
  int nx_og = 0, nx_src = 0, nx_dst = -1;
  bool nx_valid = false;
  {
    const int cb0 = t0 & 1;
    if (tid < 8) {
      int idx = t0 * 8 + tid;
      bool v = idx < E;
      int og = order[v ? idx : 0];
      s_meta[cb0][tid]      = v ? og : 0;
      s_meta[cb0][8 + tid]  = v ? esrc[og] : 0;
      s_meta[cb0][16 + tid] = v ? edst[og] : -1;
      int idx1 = (t0 + 1) * 8 + tid;
      nx_valid = idx1 < E;
      nx_og  = order[nx_valid ? idx1 : 0];
      nx_src = esrc[nx_og];
      nx_dst = edst[nx_og];
    }
  }
  __syncthreads();

  float xv[25];
  float wv[20];
  __align__(16) float ev[16];

  // group build for t0 + prefetch t0
  {
    const int cb0 = t0 & 1;
    if (wid == 0) {
      int* mb = s_meta[cb0];
      int dj = (lane < 8) ? mb[16 + lane] : -1;
      bool valid = (lane < 8) && (dj >= 0);
      bool is_start = valid && (lane == 0 || dj != mb[16 + lane - 1]);
      unsigned long long vm = __ballot(valid);
      unsigned long long sm = __ballot(is_start);
      int nv = __popcll(vm);
      int ng = __popcll(sm);
      if (lane == 0) mb[24] = ng;
      if ((int)lane < ng) {
        int s = -1, c = -1;
        for (int b = 0; b < 8; ++b) { if ((sm >> b) & 1) { ++c; if (c == (int)lane) { s = b; break; } } }
        int e_ = nv;
        for (int b = s + 1; b < 8; ++b) if ((sm >> b) & 1) { e_ = b; break; }
        int d = mb[16 + s];
        mb[25 + lane] = d;
        mb[33 + lane] = s;
        mb[41 + lane] = e_;
        mb[49 + lane] = ((e_ - s) == cnt[d]) ? 1 : 0;
      }
    }
    do_prefetch(s_meta[cb0], x, wig, efc, tid, l15, lg, xv, wv, ev);
  }

  // ---------------- persistent tile loop ----------------
  for (int t = t0; t < t_end; ++t) {
    const int cb = t & 1, nb = cb ^ 1;

    // ========== A: stage regs -> LDS, pad zeroing, meta rotate ==========
    #pragma unroll
    for (int i = 0; i < 25; ++i) {
      int o = tid + i * 256;
      int e = o / 800, q = o - e * 800;
      s_buf[e * 1304 + (q & 31) * 40 + (q >> 5)] = f2bf(xv[i]);
    }
    #pragma unroll
    for (int i = 0; i < 20; ++i) {
      int o = tid + i * 256;
      if (o < 5000) {
        int e = o / 625, q = o - e * 625;
        int i2 = q / 25, j = q - i2 * 25;
        s_wig[e * 1280 + i2 * 40 + j] = f2bf(wv[i]);
      }
    }
    // zero xe^T K-pad slab: rows 0-31, cols 25-31 per edge
    for (int o = tid; o < 1792; o += 256) {
      int e = o / 224, q = o - e * 224;
      int r = q / 7, c2 = 25 + (q - r * 7);
      s_buf[e * 1304 + r * 40 + c2] = 0;
    }
    // re-zero s_xr edge-8 zero row (polluted by yb overlay)
    for (int o = tid; o < 652; o += 256) ((int*)(s_xr + 8 * 1304))[o] = 0;
    // meta rotate: write meta(t+1), issue meta(t+2)
    if (tid < 8) {
      int* mbn = s_meta[nb];
      mbn[tid]      = nx_og;
      mbn[8 + tid]  = nx_src;
      mbn[16 + tid] = nx_valid ? nx_dst : -1;
      int idx2 = (t + 2) * 8 + tid;
      nx_valid = idx2 < E;
      nx_og  = order[nx_valid ? idx2 : 0];
      nx_src = esrc[nx_og];
      nx_dst = edst[nx_og];
    }
    __syncthreads();

    // ========== B: silu-MFMA, fwd rotation, group-build(t+1), prefetch(t+1) ==========
    // convert efc frags BEFORE ev is overwritten by prefetch
    short8 af0, af1;
    #pragma unroll
    for (int j = 0; j < 8; ++j) { af0[j] = f2bf(ev[j]); af1[j] = f2bf(ev[8 + j]); }

    do_prefetch(s_meta[nb], x, wig, efc, tid, l15, lg, xv, wv, ev);

    if (wid == 0) {     // parallel ballot group-build for t+1
      int* mb = s_meta[nb];
      int dj = (lane < 8) ? mb[16 + lane] : -1;
      bool valid = (lane < 8) && (dj >= 0);
      bool is_start = valid && (lane == 0 || dj != mb[16 + lane - 1]);
      unsigned long long vm = __ballot(valid);
      unsigned long long sm = __ballot(is_start);
      int nv = __popcll(vm);
      int ng = __popcll(sm);
      if (lane == 0) mb[24] = ng;
      if ((int)lane < ng) {
        int s = -1, c = -1;
        for (int b = 0; b < 8; ++b) { if ((sm >> b) & 1) { ++c; if (c == (int)lane) { s = b; break; } } }
        int e_ = nv;
        for (int b = s + 1; b < 8; ++b) if ((sm >> b) & 1) { e_ = b; break; }
        int d = mb[16 + s];
        mb[25 + lane] = d;
        mb[33 + lane] = s;
        mb[41 + lane] = e_;
        mb[49 + lane] = ((e_ - s) == cnt[d]) ? 1 : 0;
      }
    }

    // silu scale via MFMA: [8 edges x 64] @ fcwT -> [8 x 160]
    for (int nt = wid; nt < 10; nt += 4) {
      const int f = nt * 16 + l15;
      const short* bp = g_fcwt + f * 64 + lg * 8;
      short8 b0 = *(const short8*)(bp);
      short8 b1 = *(const short8*)(bp + 32);
      f32x4 acc = {0.f, 0.f, 0.f, 0.f};
      acc = MFMA16(af0, b0, acc);
      acc = MFMA16(af1, b1, acc);
      float bias = fcb[f];
      #pragma unroll
      for (int r = 0; r < 4; ++r) {
        int e = lg * 4 + r;
        if (e < 8) {
          float v = acc[r] + bias;
          s_sc[e * 165 + (f >> 5) * 33 + (f & 31)] = v / (1.f + __expf(-v));
        }
      }
    }

    // forward rotation: xr = W @ xe (2 edges per wave)
    #pragma unroll
    for (int i = 0; i < 2; ++i) {
      const int e = wid * 2 + i;
      const short* xeb = s_buf + e * 1304;
      const short* wgb = s_wig + e * 1280;
      short8 a0 = *(const short8*)(xeb + l15 * 40 + lg * 8);
      short8 a1 = *(const short8*)(xeb + (16 + l15) * 40 + lg * 8);
      short8 b0 = *(const short8*)(wgb + l15 * 40 + lg * 8);
      short8 b1 = *(const short8*)(wgb + (16 + l15) * 40 + lg * 8);
      f32x4 d00 = {0.f,0.f,0.f,0.f}, d01 = {0.f,0.f,0.f,0.f};
      f32x4 d10 = {0.f,0.f,0.f,0.f}, d11 = {0.f,0.f,0.f,0.f};
      d00 = MFMA16(a0, b0, d00);
      d01 = MFMA16(a0, b1, d01);
      d10 = MFMA16(a1, b0, d10);
      d11 = MFMA16(a1, b1, d11);
      short* xrb = s_xr + e * 1304;
      short4v v;
      v[0]=f2bf(d00[0]); v[1]=f2bf(d00[1]); v[2]=f2bf(d00[2]); v[3]=f2bf(d00[3]);
      *(short4v*)(xrb + l15 * 40 + lg * 4) = v;
      v[0]=f2bf(d10[0]); v[1]=f2bf(d10[1]); v[2]=f2bf(d10[2]); v[3]=f2bf(d10[3]);
      *(short4v*)(xrb + l15 * 40 + 16 + lg * 4) = v;
      v[0]=f2bf(d01[0]); v[1]=f2bf(d01[1]); v[2]=f2bf(d01[2]); v[3]=f2bf(d01[3]);
      *(short4v*)(xrb + (16 + l15) * 40 + lg * 4) = v;
      v[0]=f2bf(d11[0]); v[1]=f2bf(d11[1]); v[2]=f2bf(d11[2]); v[3]=f2bf(d11[3]);
      *(short4v*)(xrb + (16 + l15) * 40 + 16 + lg * 4) = v;
    }
    __syncthreads();

    // ========== C: y K-pad zero + SO(2) mixing ==========
    for (int o = tid; o < 1120; o += 256) {
      int e = o / 140, q = o - e * 140;
      int k = 25 + (q / 20), cp = q % 20;
      ((int*)s_buf)[e * 652 + k * 20 + cp] = 0;
    }
    const int ez = (l15 < 8) ? l15 : 8;
    for (int u = wid; u < 50; u += 4) {
      const int m = c_um[u], h = c_uh[u], tt = c_ut[u];
      const int col  = tt * 16 + l15;
      const int koff = lg * 8;
      const short* xrl = s_xr + ez * 1304 + koff;
      f32x4 acc = {0.f,0.f,0.f,0.f};
      if (m == 0) {
        const short* B = g_wt + col * 160 + koff;
        #pragma unroll 5
        for (int ks = 0; ks < 5; ++ks) {
          short8 a = *(const short8*)(xrl + c_P[0][ks] * 40);
          short8 b = *(const short8*)(B + ks * 32);
          acc = MFMA16(a, b, acc);
        }
      } else {
        const int dm = (5 - m) * 32;
        const int lm = 5 - m;
        const short* B1 = g_wt + (h == 0 ? c_wr[m]  : c_wi[m]) + col * dm + koff;
        const short* B2 = g_wt + (h == 0 ? c_nwi[m] : c_wr[m]) + col * dm + koff;
        #pragma unroll 4
        for (int ks = 0; ks < 4; ++ks) if (ks < lm) {
          short8 ap = *(const short8*)(xrl + c_P[m][ks] * 40);
          short8 b1 = *(const short8*)(B1 + ks * 32);
          acc = MFMA16(ap, b1, acc);
          short8 an = *(const short8*)(xrl + c_Ng[m][ks] * 40);
          short8 b2 = *(const short8*)(B2 + ks * 32);
          acc = MFMA16(an, b2, acc);
        }
      }
      const int lo = col >> 5, co = col & 31;
      const int coeff = (h == 0) ? c_P[m][lo] : c_Ng[m][lo];
      const int lsc = m + lo;
      #pragma unroll 4
      for (int r = 0; r < 4; ++r) {
        const int e = lg * 4 + r;
        if (e < 8) {
          float sc = s_sc[e * 165 + lsc * 33 + co];
          s_buf[e * 1304 + coeff * 40 + co] = f2bf(acc[r] * sc);
        }
      }
    }
    __syncthreads();

    // ========== D: back-rotation yb = W^T @ y (regs) ==========
    f32x4 r00[2], r01[2], r10[2], r11[2];
    #pragma unroll
    for (int i = 0; i < 2; ++i) {
      const int e = wid * 2 + i;
      const short* yb  = s_buf + e * 1304 + lg * 8 * 40;
      const short* wgb = s_wig + e * 1280 + lg * 8 * 40;
      short8 a0, a1, b0, b1;
      #pragma unroll 8
      for (int j = 0; j < 8; ++j) {
        a0[j] = yb[j * 40 + l15];
        a1[j] = yb[j * 40 + 16 + l15];
        b0[j] = wgb[j * 40 + l15];
        b1[j] = wgb[j * 40 + 16 + l15];
      }
      f32x4 d00 = {0.f,0.f,0.f,0.f}, d01 = {0.f,0.f,0.f,0.f};
      f32x4 d10 = {0.f,0.f,0.f,0.f}, d11 = {0.f,0.f,0.f,0.f};
      d00 = MFMA16(a0, b0, d00);
      d01 = MFMA16(a0, b1, d01);
      d10 = MFMA16(a1, b0, d10);
      d11 = MFMA16(a1, b1, d11);
      r00[i] = d00; r01[i] = d01; r10[i] = d10; r11[i] = d11;
    }
    __syncthreads();

    // ========== E: yb -> LDS overlay ==========
    #pragma unroll
    for (int i = 0; i < 2; ++i) {
      const int e = wid * 2 + i;
      float* yb = yb_s + e * 840;
      #pragma unroll 4
      for (int r = 0; r < 4; ++r) {
        yb[l15 * 33 + lg * 4 + r]      = r00[i][r];
        yb[l15 * 33 + 16 + lg * 4 + r] = r10[i][r];
      }
      if (l15 < 9) {
        #pragma unroll 4
        for (int r = 0; r < 4; ++r) {
          yb[(16 + l15) * 33 + lg * 4 + r]      = r01[i][r];
          yb[(16 + l15) * 33 + 16 + lg * 4 + r] = r11[i][r];
        }
      }
    }
    __syncthreads();

    // ========== F: segmented flush ==========
    {
      const int* mcb = s_meta[cb];
      const int ng = mcb[24];
      for (int o = tid; o < 800; o += 256) {
        const int yoff = (o >> 5) * 33 + (o & 31);
        for (int g = 0; g < ng; ++g) {
          float sum = 0.f;
          const int gs = mcb[33 + g], ge = mcb[41 + g];
          for (int e = gs; e < ge; ++e) sum += yb_s[e * 840 + yoff];
          float* ad = out + (size_t)mcb[25 + g] * 800 + o;
          if (mcb[49 + g]) *ad = sum;
          else atomicAdd(ad, sum);
        }
      }
    }
    __syncthreads();
  }
}

extern "C" void kernel_launch(void* const* d_in, const int* in_sizes, int n_in,
                              void* d_out, int out_size, void* d_ws, size_t ws_size,
                              hipStream_t stream) {
  const float* x    = (const float*)d_in[0];
  const float* wigp = (const float*)d_in[1];
  const float* efc  = (const float*)d_in[2];
  const int*   esrc = (const int*)d_in[3];
  const int*   edst = (const int*)d_in[4];
  const float* w0   = (const float*)d_in[5];
  const float* w1r  = (const float*)d_in[6];
  const float* w1i  = (const float*)d_in[7];
  const float* w2r  = (const float*)d_in[8];
  const float* w2i  = (const float*)d_in[9];
  const float* w3r  = (const float*)d_in[10];
  const float* w3i  = (const float*)d_in[11];
  const float* w4r  = (const float*)d_in[12];
  const float* w4i  = (const float*)d_in[13];
  const float* fcw  = (const float*)d_in[14];
  const float* fcb  = (const float*)d_in[15];
  float* out = (float*)d_out;
  const int E = in_sizes[3];
  const int N = out_size / 800;

  int* cnt    = (int*)d_ws;
  int* cursor = cnt + N;
  int* order  = cnt + 2 * N;

  hipFuncSetAttribute((const void*)so2_mfma_kernel,
                      hipFuncAttributeMaxDynamicSharedMemorySize, SMEM_BYTES);

  prep_weights<<<(128000 + 255) / 256, 256, 0, stream>>>(
      w0, w1r, w1i, w2r, w2i, w3r, w3i, w4r, w4i, fcw);

  hipMemsetAsync(d_out, 0, (size_t)out_size * sizeof(float), stream);
  hipMemsetAsync(cnt, 0, (size_t)N * sizeof(int), stream);

  hist_kernel<<<(E + 255) / 256, 256, 0, stream>>>(edst, cnt, E);
  scan_kernel<<<1, 1024, 0, stream>>>(cnt, cursor, N);
  scatter_kernel<<<(E + 255) / 256, 256, 0, stream>>>(edst, cursor, order, E);

  so2_mfma_kernel<<<NBLK, 256, SMEM_BYTES, stream>>>(
      x, wigp, efc, esrc, edst, fcb, cnt, order, out, E);
}

// Round 5
// 1393.344 us; speedup vs baseline: 2.0003x; 1.4959x over previous
//
#include <hip/hip_runtime.h>

typedef __attribute__((ext_vector_type(8))) short short8;
typedef __attribute__((ext_vector_type(4))) short short4v;
typedef __attribute__((ext_vector_type(4))) float f32x4;

#define MFMA16(a,b,c) __builtin_amdgcn_mfma_f32_16x16x32_bf16((a),(b),(c),0,0,0)

// Pre-transposed bf16 mixing weights: w0T | w1rT w1iT -w1iT | ... | w4iT -w4iT
__device__ __align__(16) short g_wt[117760];
// Pre-transposed bf16 radial weights fcwT[160][64]
__device__ __align__(16) short g_fcwt[10240];

__constant__ int c_P[5][5] = {
  {0, 2, 6, 12, 20},
  {3, 7, 13, 21, 0},
  {8, 14, 22, 0, 0},
  {15, 23, 0, 0, 0},
  {24, 0, 0, 0, 0}};
__constant__ int c_Ng[5][5] = {
  {0, 2, 6, 12, 20},
  {1, 5, 11, 19, 0},
  {4, 10, 18, 0, 0},
  {9, 17, 0, 0, 0},
  {16, 0, 0, 0, 0}};
__constant__ int c_wr[5]  = {0, 25600, 74752, 102400, 114688};
__constant__ int c_wi[5]  = {0, 41984, 83968, 106496, 115712};
__constant__ int c_nwi[5] = {0, 58368, 93184, 110592, 116736};
__constant__ unsigned char c_um[50] = {1,1,1,1,1,1,1,1, 1,1,1,1,1,1,1,1, 2,2,2,2,2,2, 2,2,2,2,2,2, 0,0,0,0,0,0,0,0,0,0, 3,3,3,3, 3,3,3,3, 4,4, 4,4};
__constant__ unsigned char c_uh[50] = {0,0,0,0,0,0,0,0, 1,1,1,1,1,1,1,1, 0,0,0,0,0,0, 1,1,1,1,1,1, 0,0,0,0,0,0,0,0,0,0, 0,0,0,0, 1,1,1,1, 0,0, 1,1};
__constant__ unsigned char c_ut[50] = {0,1,2,3,4,5,6,7, 0,1,2,3,4,5,6,7, 0,1,2,3,4,5, 0,1,2,3,4,5, 0,1,2,3,4,5,6,7,8,9, 0,1,2,3, 0,1,2,3, 0,1, 0,1};

__device__ __forceinline__ short f2bf(float f) {
  unsigned u = __float_as_uint(f);
  u += 0x7FFFu + ((u >> 16) & 1u);
  return (short)(u >> 16);
}

__global__ void prep_weights(const float* __restrict__ w0,
    const float* __restrict__ w1r, const float* __restrict__ w1i,
    const float* __restrict__ w2r, const float* __restrict__ w2i,
    const float* __restrict__ w3r, const float* __restrict__ w3i,
    const float* __restrict__ w4r, const float* __restrict__ w4i,
    const float* __restrict__ fcw) {
  int idx = blockIdx.x * 256 + threadIdx.x;
  if (idx >= 128000) return;
  if (idx >= 117760) {
    int local = idx - 117760;
    int n = local >> 6, k = local & 63;
    g_fcwt[local] = f2bf(fcw[k * 160 + n]);
    return;
  }
  int off, dm; const float* src; bool neg = false;
  if (idx < 25600)       { off = 0;      dm = 160; src = w0;  }
  else if (idx < 41984)  { off = 25600;  dm = 128; src = w1r; }
  else if (idx < 58368)  { off = 41984;  dm = 128; src = w1i; }
  else if (idx < 74752)  { off = 58368;  dm = 128; src = w1i; neg = true; }
  else if (idx < 83968)  { off = 74752;  dm = 96;  src = w2r; }
  else if (idx < 93184)  { off = 83968;  dm = 96;  src = w2i; }
  else if (idx < 102400) { off = 93184;  dm = 96;  src = w2i; neg = true; }
  else if (idx < 106496) { off = 102400; dm = 64;  src = w3r; }
  else if (idx < 110592) { off = 106496; dm = 64;  src = w3i; }
  else if (idx < 114688) { off = 110592; dm = 64;  src = w3i; neg = true; }
  else if (idx < 115712) { off = 114688; dm = 32;  src = w4r; }
  else if (idx < 116736) { off = 115712; dm = 32;  src = w4i; }
  else                   { off = 116736; dm = 32;  src = w4i; neg = true; }
  int local = idx - off;
  int n = local / dm, k = local - n * dm;
  float v = src[k * dm + n];
  g_wt[idx] = f2bf(neg ? -v : v);
}

// ---------------- counting sort of edges by dst ----------------
__global__ void hist_kernel(const int* __restrict__ edst, int* __restrict__ cnt, int E) {
  int i = blockIdx.x * 256 + threadIdx.x;
  if (i < E) atomicAdd(&cnt[edst[i]], 1);
}

__global__ __launch_bounds__(1024) void scan_kernel(
    const int* __restrict__ cnt, int* __restrict__ cursor, int N) {
  __shared__ int s[1024];
  const int t = threadIdx.x;
  int v[10]; int sum = 0;
  #pragma unroll
  for (int k = 0; k < 10; ++k) {
    int i = t * 10 + k;
    v[k] = (i < N) ? cnt[i] : 0;
    sum += v[k];
  }
  s[t] = sum;
  __syncthreads();
  for (int d = 1; d < 1024; d <<= 1) {
    int add = (t >= d) ? s[t - d] : 0;
    __syncthreads();
    s[t] += add;
    __syncthreads();
  }
  int prefix = s[t] - sum;   // exclusive
  #pragma unroll
  for (int k = 0; k < 10; ++k) {
    int i = t * 10 + k;
    if (i < N) cursor[i] = prefix;
    prefix += v[k];
  }
}

__global__ void scatter_kernel(const int* __restrict__ edst, int* __restrict__ cursor,
                               int* __restrict__ order, int E) {
  int i = blockIdx.x * 256 + threadIdx.x;
  if (i < E) {
    int p = atomicAdd(&cursor[edst[i]], 1);
    order[p] = i;
  }
}

// ================= K1: gather + forward rotation, permuted to sorted order =================
// xr[slot][coeff*32+ch] bf16, slot = sorted position
__global__ __launch_bounds__(256) void k1_rotate(
    const float* __restrict__ x, const float* __restrict__ wig,
    const int* __restrict__ esrc, const int* __restrict__ order,
    short* __restrict__ xr, int E)
{
  __shared__ short s_xe[8 * 1304];   // [e][ch*40+coeff]
  __shared__ short s_wg[8 * 1280];   // [e][i*40+j]
  __shared__ int s_og[8], s_src[8];

  const int tid = threadIdx.x;
  const int lane = tid & 63;
  const int wid = tid >> 6;
  const int l15 = lane & 15;
  const int lg  = lane >> 4;
  const int e0  = blockIdx.x * 8;

  for (int o = tid; o < 5216; o += 256) ((int*)s_xe)[o] = 0;
  for (int o = tid; o < 5120; o += 256) ((int*)s_wg)[o] = 0;
  if (tid < 8) {
    int idx = min(e0 + tid, E - 1);
    int og = order[idx];
    s_og[tid] = og;
    s_src[tid] = esrc[og];
  }
  __syncthreads();

  for (int o = tid; o < 6400; o += 256) {
    int e = o / 800, q = o - e * 800;
    s_xe[e * 1304 + (q & 31) * 40 + (q >> 5)] = f2bf(x[(size_t)s_src[e] * 800 + q]);
  }
  for (int o = tid; o < 5000; o += 256) {
    int e = o / 625, q = o - e * 625;
    int i = q / 25, j = q - i * 25;
    s_wg[e * 1280 + i * 40 + j] = f2bf(wig[(size_t)s_og[e] * 625 + q]);
  }
  __syncthreads();

  #pragma unroll
  for (int i = 0; i < 2; ++i) {
    const int e = wid * 2 + i;
    const int slot = e0 + e;
    if (slot >= E) continue;
    const short* xeb = s_xe + e * 1304;
    const short* wgb = s_wg + e * 1280;
    short8 a0 = *(const short8*)(xeb + l15 * 40 + lg * 8);          // ch 0-15
    short8 a1 = *(const short8*)(xeb + (16 + l15) * 40 + lg * 8);   // ch 16-31
    short8 b0 = *(const short8*)(wgb + l15 * 40 + lg * 8);          // coeff 0-15
    short8 b1 = *(const short8*)(wgb + (16 + l15) * 40 + lg * 8);   // coeff 16-31
    f32x4 d00 = {0.f,0.f,0.f,0.f}, d01 = {0.f,0.f,0.f,0.f};
    f32x4 d10 = {0.f,0.f,0.f,0.f}, d11 = {0.f,0.f,0.f,0.f};
    d00 = MFMA16(a0, b0, d00);
    d01 = MFMA16(a0, b1, d01);
    d10 = MFMA16(a1, b0, d10);
    d11 = MFMA16(a1, b1, d11);
    short* xp = xr + (size_t)slot * 800;
    short4v v;
    v[0]=f2bf(d00[0]); v[1]=f2bf(d00[1]); v[2]=f2bf(d00[2]); v[3]=f2bf(d00[3]);
    *(short4v*)(xp + l15 * 32 + lg * 4) = v;                         // coeff=l15, ch=lg*4+r
    v[0]=f2bf(d10[0]); v[1]=f2bf(d10[1]); v[2]=f2bf(d10[2]); v[3]=f2bf(d10[3]);
    *(short4v*)(xp + l15 * 32 + 16 + lg * 4) = v;
    if (l15 < 9) {
      v[0]=f2bf(d01[0]); v[1]=f2bf(d01[1]); v[2]=f2bf(d01[2]); v[3]=f2bf(d01[3]);
      *(short4v*)(xp + (16 + l15) * 32 + lg * 4) = v;
      v[0]=f2bf(d11[0]); v[1]=f2bf(d11[1]); v[2]=f2bf(d11[2]); v[3]=f2bf(d11[3]);
      *(short4v*)(xp + (16 + l15) * 32 + 16 + lg * 4) = v;
    }
  }
}

// ================= K2: SO(2) mixing + silu scale, in-place xr -> y =================
__global__ __launch_bounds__(256) void k2_mix(
    short* __restrict__ xr, const float* __restrict__ efc,
    const int* __restrict__ order, const float* __restrict__ fcb, int E)
{
  __shared__ short s_x[16 * 808];    // [e][coeff*32+ch] (+8 pad per row)
  __shared__ short s_y[16 * 808];
  __shared__ float s_sc[16 * 165];

  const int tid = threadIdx.x;
  const int lane = tid & 63;
  const int wid = tid >> 6;
  const int l15 = lane & 15;
  const int lg  = lane >> 4;
  const int e0  = blockIdx.x * 16;

  // stage xr tile (coalesced 16B)
  for (int o = tid; o < 1600; o += 256) {
    int e = o / 100, q = o * 8 - e * 800;
    int slot = min(e0 + e, E - 1);
    *(short8*)(s_x + e * 808 + q) = *(const short8*)(xr + (size_t)slot * 800 + q);
  }

  // silu scale via MFMA: rows = 16 edges, cols = 160 features
  {
    const int ge = order[min(e0 + l15, E - 1)];
    const float* ep = efc + (size_t)ge * 64;
    float4 fa = *(const float4*)(ep + lg * 8);
    float4 fb = *(const float4*)(ep + lg * 8 + 4);
    float4 fc = *(const float4*)(ep + 32 + lg * 8);
    float4 fd = *(const float4*)(ep + 32 + lg * 8 + 4);
    short8 af0, af1;
    #pragma unroll
    for (int j = 0; j < 4; ++j) {
      af0[j] = f2bf(fa[j]); af0[4 + j] = f2bf(fb[j]);
      af1[j] = f2bf(fc[j]); af1[4 + j] = f2bf(fd[j]);
    }
    for (int nt = wid; nt < 10; nt += 4) {
      const int f = nt * 16 + l15;
      const short* bp = g_fcwt + f * 64 + lg * 8;
      short8 b0 = *(const short8*)(bp);
      short8 b1 = *(const short8*)(bp + 32);
      f32x4 acc = {0.f, 0.f, 0.f, 0.f};
      acc = MFMA16(af0, b0, acc);
      acc = MFMA16(af1, b1, acc);
      float bias = fcb[f];
      #pragma unroll
      for (int r = 0; r < 4; ++r) {
        float vv = acc[r] + bias;
        s_sc[(lg * 4 + r) * 165 + (f >> 5) * 33 + (f & 31)] = vv / (1.f + __expf(-vv));
      }
    }
  }
  __syncthreads();

  // mixing: 50 units, M = 16 edges, A from s_x, B from g_wt (L2-resident)
  for (int u = wid; u < 50; u += 4) {
    const int m = c_um[u], h = c_uh[u], tt = c_ut[u];
    const int col = tt * 16 + l15;
    const int koff = lg * 8;
    const short* xl = s_x + l15 * 808 + koff;   // row = edge = l15
    f32x4 acc = {0.f,0.f,0.f,0.f};
    if (m == 0) {
      const short* B = g_wt + col * 160 + koff;
      #pragma unroll 5
      for (int ks = 0; ks < 5; ++ks) {
        short8 a = *(const short8*)(xl + c_P[0][ks] * 32);
        short8 b = *(const short8*)(B + ks * 32);
        acc = MFMA16(a, b, acc);
      }
    } else {
      const int dm = (5 - m) * 32;
      const int lm = 5 - m;
      const short* B1 = g_wt + (h == 0 ? c_wr[m]  : c_wi[m]) + col * dm + koff;
      const short* B2 = g_wt + (h == 0 ? c_nwi[m] : c_wr[m]) + col * dm + koff;
      #pragma unroll 4
      for (int ks = 0; ks < 4; ++ks) if (ks < lm) {
        short8 ap = *(const short8*)(xl + c_P[m][ks] * 32);
        short8 b1 = *(const short8*)(B1 + ks * 32);
        acc = MFMA16(ap, b1, acc);
        short8 an = *(const short8*)(xl + c_Ng[m][ks] * 32);
        short8 b2 = *(const short8*)(B2 + ks * 32);
        acc = MFMA16(an, b2, acc);
      }
    }
    const int lo = col >> 5, co = col & 31;
    const int coeff = (h == 0) ? c_P[m][lo] : c_Ng[m][lo];
    const int lsc = m + lo;
    #pragma unroll 4
    for (int r = 0; r < 4; ++r) {
      const int e = lg * 4 + r;
      float sc = s_sc[e * 165 + lsc * 33 + co];
      s_y[e * 808 + coeff * 32 + co] = f2bf(acc[r] * sc);
    }
  }
  __syncthreads();

  // flush y in place over xr (coalesced 16B)
  for (int o = tid; o < 1600; o += 256) {
    int e = o / 100, q = o * 8 - e * 800;
    int slot = e0 + e;
    if (slot < E)
      *(short8*)(xr + (size_t)slot * 800 + q) = *(const short8*)(s_y + e * 808 + q);
  }
}

// ================= K3: back-rotation + segmented sorted flush =================
__global__ __launch_bounds__(256) void k3_back(
    const short* __restrict__ y, const float* __restrict__ wig,
    const int* __restrict__ edst, const int* __restrict__ order,
    const int* __restrict__ cnt, float* __restrict__ out, int E)
{
  __shared__ short smem[20672];      // s_wg [8*1280] @0 | s_y [8*1304] @10240; yb f32 overlay @0 (13440 shorts)
  __shared__ int s_meta[64];
  short* s_wg = smem;
  short* s_y  = smem + 10240;        // [e][coeff*40+ch]
  float* yb_s = (float*)smem;        // [e][840]

  const int tid = threadIdx.x;
  const int lane = tid & 63;
  const int wid = tid >> 6;
  const int l15 = lane & 15;
  const int lg  = lane >> 4;
  const int e0  = blockIdx.x * 8;

  for (int o = tid; o < 10336; o += 256) ((int*)smem)[o] = 0;
  if (tid < 8) {
    int idx = e0 + tid;
    bool v = idx < E;
    int og = order[v ? idx : 0];
    s_meta[tid] = og;
    s_meta[16 + tid] = v ? edst[og] : -1;
  }
  __syncthreads();

  if (wid == 0) {          // ballot group build
    int dj = (lane < 8) ? s_meta[16 + lane] : -1;
    bool valid = (lane < 8) && (dj >= 0);
    bool is_start = valid && (lane == 0 || dj != s_meta[16 + lane - 1]);
    unsigned long long vm = __ballot(valid);
    unsigned long long sm = __ballot(is_start);
    int nv = __popcll(vm);
    int ng = __popcll(sm);
    if (lane == 0) s_meta[24] = ng;
    if ((int)lane < ng) {
      int s = -1, c = -1;
      for (int b = 0; b < 8; ++b) { if ((sm >> b) & 1) { ++c; if (c == (int)lane) { s = b; break; } } }
      int e_ = nv;
      for (int b = s + 1; b < 8; ++b) if ((sm >> b) & 1) { e_ = b; break; }
      int d = s_meta[16 + s];
      s_meta[25 + lane] = d;
      s_meta[33 + lane] = s;
      s_meta[41 + lane] = e_;
      s_meta[49 + lane] = ((e_ - s) == cnt[d]) ? 1 : 0;
    }
  }
  for (int o = tid; o < 5000; o += 256) {
    int e = o / 625, q = o - e * 625;
    int i = q / 25, j = q - i * 25;
    s_wg[e * 1280 + i * 40 + j] = f2bf(wig[(size_t)s_meta[e] * 625 + q]);
  }
  for (int o = tid; o < 800; o += 256) {
    int e = o / 100, q = o * 8 - e * 800;
    int slot = min(e0 + e, E - 1);
    *(short8*)(s_y + e * 1304 + (q >> 5) * 40 + (q & 31)) =
        *(const short8*)(y + (size_t)slot * 800 + q);
  }
  __syncthreads();

  // back-rotate: yb = W^T @ y, 2 edges per wave, results in regs
  f32x4 r00[2], r01[2], r10[2], r11[2];
  #pragma unroll
  for (int i = 0; i < 2; ++i) {
    const int e = wid * 2 + i;
    const short* yb  = s_y + e * 1304 + lg * 8 * 40;
    const short* wgb = s_wg + e * 1280 + lg * 8 * 40;
    short8 a0, a1, b0, b1;
    #pragma unroll 8
    for (int j = 0; j < 8; ++j) {
      a0[j] = yb[j * 40 + l15];
      a1[j] = yb[j * 40 + 16 + l15];
      b0[j] = wgb[j * 40 + l15];
      b1[j] = wgb[j * 40 + 16 + l15];
    }
    f32x4 d00 = {0.f,0.f,0.f,0.f}, d01 = {0.f,0.f,0.f,0.f};
    f32x4 d10 = {0.f,0.f,0.f,0.f}, d11 = {0.f,0.f,0.f,0.f};
    d00 = MFMA16(a0, b0, d00);
    d01 = MFMA16(a0, b1, d01);
    d10 = MFMA16(a1, b0, d10);
    d11 = MFMA16(a1, b1, d11);
    r00[i] = d00; r01[i] = d01; r10[i] = d10; r11[i] = d11;
  }
  __syncthreads();

  // overlay yb (f32) over smem
  #pragma unroll
  for (int i = 0; i < 2; ++i) {
    const int e = wid * 2 + i;
    float* yb = yb_s + e * 840;
    #pragma unroll 4
    for (int r = 0; r < 4; ++r) {
      yb[l15 * 33 + lg * 4 + r]      = r00[i][r];
      yb[l15 * 33 + 16 + lg * 4 + r] = r10[i][r];
    }
    if (l15 < 9) {
      #pragma unroll 4
      for (int r = 0; r < 4; ++r) {
        yb[(16 + l15) * 33 + lg * 4 + r]      = r01[i][r];
        yb[(16 + l15) * 33 + 16 + lg * 4 + r] = r11[i][r];
      }
    }
  }
  __syncthreads();

  // segmented flush: one add/store per (dst-group, element)
  const int ng = s_meta[24];
  for (int o = tid; o < 800; o += 256) {
    const int yoff = (o >> 5) * 33 + (o & 31);
    for (int g = 0; g < ng; ++g) {
      float sum = 0.f;
      const int gs = s_meta[33 + g], ge = s_meta[41 + g];
      for (int e = gs; e < ge; ++e) sum += yb_s[e * 840 + yoff];
      float* ad = out + (size_t)s_meta[25 + g] * 800 + o;
      if (s_meta[49 + g]) *ad = sum;
      else atomicAdd(ad, sum);
    }
  }
}

extern "C" void kernel_launch(void* const* d_in, const int* in_sizes, int n_in,
                              void* d_out, int out_size, void* d_ws, size_t ws_size,
                              hipStream_t stream) {
  const float* x    = (const float*)d_in[0];
  const float* wigp = (const float*)d_in[1];
  const float* efc  = (const float*)d_in[2];
  const int*   esrc = (const int*)d_in[3];
  const int*   edst = (const int*)d_in[4];
  const float* w0   = (const float*)d_in[5];
  const float* w1r  = (const float*)d_in[6];
  const float* w1i  = (const float*)d_in[7];
  const float* w2r  = (const float*)d_in[8];
  const float* w2i  = (const float*)d_in[9];
  const float* w3r  = (const float*)d_in[10];
  const float* w3i  = (const float*)d_in[11];
  const float* w4r  = (const float*)d_in[12];
  const float* w4i  = (const float*)d_in[13];
  const float* fcw  = (const float*)d_in[14];
  const float* fcb  = (const float*)d_in[15];
  float* out = (float*)d_out;
  const int E = in_sizes[3];
  const int N = out_size / 800;

  int* cnt    = (int*)d_ws;
  int* cursor = cnt + N;
  int* order  = cnt + 2 * N;
  size_t xr_off = (((size_t)(2 * N + E) * 4) + 255) & ~(size_t)255;
  short* xr = (short*)((char*)d_ws + xr_off);   // E*800 bf16 = 256 MB

  prep_weights<<<(128000 + 255) / 256, 256, 0, stream>>>(
      w0, w1r, w1i, w2r, w2i, w3r, w3i, w4r, w4i, fcw);

  hipMemsetAsync(d_out, 0, (size_t)out_size * sizeof(float), stream);
  hipMemsetAsync(cnt, 0, (size_t)N * sizeof(int), stream);

  hist_kernel<<<(E + 255) / 256, 256, 0, stream>>>(edst, cnt, E);
  scan_kernel<<<1, 1024, 0, stream>>>(cnt, cursor, N);
  scatter_kernel<<<(E + 255) / 256, 256, 0, stream>>>(edst, cursor, order, E);

  k1_rotate<<<(E + 7) / 8, 256, 0, stream>>>(x, wigp, esrc, order, xr, E);
  k2_mix<<<(E + 15) / 16, 256, 0, stream>>>(xr, efc, order, fcb, E);
  k3_back<<<(E + 7) / 8, 256, 0, stream>>>(xr, wigp, edst, order, cnt, out, E);
}